// Round 8
// baseline (939.478 us; speedup 1.0000x reference)
//
#include <hip/hip_runtime.h>

#define S_LEN 3072
#define NHQ 16
#define NKVH 8
#define HDIM 256
#define WIN 2048
#define QKV_COLS 8192

typedef __bf16 bf16x8 __attribute__((ext_vector_type(8)));
typedef float f32x4 __attribute__((ext_vector_type(4)));
typedef float f32x16 __attribute__((ext_vector_type(16)));

__device__ __forceinline__ unsigned short f2bf(float f) {
    union { float f; unsigned u; } v; v.f = f;
    unsigned r = v.u + 0x7FFFu + ((v.u >> 16) & 1u);
    return (unsigned short)(r >> 16);
}
__device__ __forceinline__ float bf2f(unsigned short u) {
    union { unsigned u; float f; } v; v.u = ((unsigned)u) << 16; return v.f;
}

typedef __attribute__((address_space(3))) void lds_void_t;
typedef const __attribute__((address_space(1))) void glb_void_t;
__device__ __forceinline__ void async16(const void* g, void* l) {
    __builtin_amdgcn_global_load_lds((glb_void_t*)g, (lds_void_t*)l, 16, 0, 0);
}

// ---------------- fp32 -> bf16 cast ----------------
__global__ __launch_bounds__(256) void cast_bf16_kernel(const float* __restrict__ src,
                                                        unsigned short* __restrict__ dst,
                                                        int n) {
    int i = (blockIdx.x * 256 + threadIdx.x) * 4;
    if (i >= n) return;
    float4 v = *(const float4*)(src + i);
    ushort4 o;
    o.x = f2bf(v.x); o.y = f2bf(v.y); o.z = f2bf(v.z); o.w = f2bf(v.w);
    *(ushort4*)(dst + i) = o;
}

// ---------------- bf16 GEMM v10: 256x256/BK=64, 8-phase interleave (T3+T4) ----
// Round-7 evidence: v9 (same geometry, swizzle verified: conflicts 2.2e7 -> 0)
// stuck at MfmaUtil 28% — the 2-phase drain-0 schedule serializes ~1200cyc/tile
// of stage+wait+LDS on top of 620cyc MFMA (the m233 stall). v10 ports the
// 8-phase schedule: per K-tile 4 phases (m-half x k-half), each
// {ds_read subtile || (ph1: issue ALL 8 next-tile DMAs) -> s_barrier ->
//  lgkmcnt(0)+sched_barrier(0) -> setprio(1) -> 16 MFMA -> setprio(0) ->
//  s_barrier}; vmcnt(0) only at the tile's final barrier (~3 phases of cover).
// bfr register-reused across m-halves: 24 ds_read_b128/tile (unchanged).
// Barrier pairs role-split the 2 waves/SIMD (ds_read || MFMA) — the T5 gate.
// Buffer safety: STAGE targets buf[rb^1], whose readers (tile t-1) all passed
// tile t-1's final barrier before phase 1 of tile t (v4/v7/v9-verified arg).
template <int OUT_BF16>
__global__ __launch_bounds__(512, 2) void gemm_bt(const unsigned short* __restrict__ A,
                                                  const unsigned short* __restrict__ B,
                                                  void* __restrict__ Cv,
                                                  int N, int K) {
    __shared__ __align__(16) unsigned short Al[2][256 * 64];   // 2 x 32 KB
    __shared__ __align__(16) unsigned short Bl[2][256 * 64];   // 2 x 32 KB
    const int tid = threadIdx.x;
    const int wid = tid >> 6, lane = tid & 63;
    const int ln = lane & 15, quad = lane >> 4;
    const int wm = wid >> 2, wn = wid & 3;     // wave tile: rows wm*128, cols wn*64

    int bm, bn;
    {
        const int nwg = gridDim.x * gridDim.y;
        int orig = blockIdx.y * gridDim.x + blockIdx.x;
        int wg = orig;
        if ((nwg & 7) == 0) {
            const int cpx = nwg >> 3;
            wg = (orig & 7) * cpx + (orig >> 3);
        }
        bm = wg / gridDim.x;
        bn = wg % gridDim.x;
    }

    const f32x4 fzero = {0.f, 0.f, 0.f, 0.f};
    f32x4 acc[8][4];
#pragma unroll
    for (int i = 0; i < 8; i++) {
#pragma unroll
        for (int j = 0; j < 4; j++) acc[i][j] = fzero;
    }

    // staging source (pre-swizzled; v9-verified): chunk slot s of row r holds
    // orig chunk s^(r&7); r&7 == (tid>>3)&7 for every DMA call.
    const unsigned short* gA = A + (size_t)(bm * 256 + (tid >> 3)) * K
                               + (((tid & 7) ^ ((tid >> 3) & 7)) * 8);
    const unsigned short* gB = B + (size_t)(bn * 256 + (tid >> 3)) * K
                               + (((tid & 7) ^ ((tid >> 3) & 7)) * 8);

    auto STAGE = [&](int k0, int b) {
#pragma unroll
        for (int c = 0; c < 4; c++)
            async16(gA + (size_t)(c * 64) * K + k0, &Al[b][(c * 512 + tid) * 8]);
#pragma unroll
        for (int c = 0; c < 4; c++)
            async16(gB + (size_t)(c * 64) * K + k0, &Bl[b][(c * 512 + tid) * 8]);
    };

    const int NT = K >> 6;                     // K/64 tiles
    STAGE(0, 0);
    int rb = 0;
    const int aswz = ln & 7;

    asm volatile("s_waitcnt vmcnt(0)" ::: "memory");
    __builtin_amdgcn_s_barrier();
    asm volatile("" ::: "memory");

    for (int t = 0; t < NT; ++t) {
        const unsigned short* al = Al[rb];
        const unsigned short* bl = Bl[rb];
        bf16x8 bfr[2][4];
        bf16x8 af[4];

        // ---- Phase 1: (mh=0, kh=0) + issue all next-tile DMAs ----
        {
            const int cs = ((0 + quad) ^ aswz) * 8;
#pragma unroll
            for (int nt = 0; nt < 4; nt++)
                bfr[0][nt] = *(const bf16x8*)(bl + (wn * 64 + nt * 16 + ln) * 64 + cs);
#pragma unroll
            for (int mt = 0; mt < 4; mt++)
                af[mt] = *(const bf16x8*)(al + (wm * 128 + mt * 16 + ln) * 64 + cs);
            if (t + 1 < NT) STAGE((t + 1) << 6, rb ^ 1);
            __builtin_amdgcn_s_barrier();
            asm volatile("s_waitcnt lgkmcnt(0)" ::: "memory");
            __builtin_amdgcn_sched_barrier(0);
            __builtin_amdgcn_s_setprio(1);
#pragma unroll
            for (int mt = 0; mt < 4; mt++) {
#pragma unroll
                for (int nt = 0; nt < 4; nt++)
                    acc[mt][nt] = __builtin_amdgcn_mfma_f32_16x16x32_bf16(af[mt], bfr[0][nt], acc[mt][nt], 0, 0, 0);
            }
            __builtin_amdgcn_s_setprio(0);
            __builtin_amdgcn_s_barrier();
        }
        // ---- Phase 2: (mh=0, kh=1) ----
        {
            const int cs = ((4 + quad) ^ aswz) * 8;
#pragma unroll
            for (int nt = 0; nt < 4; nt++)
                bfr[1][nt] = *(const bf16x8*)(bl + (wn * 64 + nt * 16 + ln) * 64 + cs);
#pragma unroll
            for (int mt = 0; mt < 4; mt++)
                af[mt] = *(const bf16x8*)(al + (wm * 128 + mt * 16 + ln) * 64 + cs);
            __builtin_amdgcn_s_barrier();
            asm volatile("s_waitcnt lgkmcnt(0)" ::: "memory");
            __builtin_amdgcn_sched_barrier(0);
            __builtin_amdgcn_s_setprio(1);
#pragma unroll
            for (int mt = 0; mt < 4; mt++) {
#pragma unroll
                for (int nt = 0; nt < 4; nt++)
                    acc[mt][nt] = __builtin_amdgcn_mfma_f32_16x16x32_bf16(af[mt], bfr[1][nt], acc[mt][nt], 0, 0, 0);
            }
            __builtin_amdgcn_s_setprio(0);
            __builtin_amdgcn_s_barrier();
        }
        // ---- Phase 3: (mh=1, kh=0) — bfr[0] reused from registers ----
        {
            const int cs = ((0 + quad) ^ aswz) * 8;
#pragma unroll
            for (int mt = 0; mt < 4; mt++)
                af[mt] = *(const bf16x8*)(al + (wm * 128 + 64 + mt * 16 + ln) * 64 + cs);
            __builtin_amdgcn_s_barrier();
            asm volatile("s_waitcnt lgkmcnt(0)" ::: "memory");
            __builtin_amdgcn_sched_barrier(0);
            __builtin_amdgcn_s_setprio(1);
#pragma unroll
            for (int mt = 0; mt < 4; mt++) {
#pragma unroll
                for (int nt = 0; nt < 4; nt++)
                    acc[4 + mt][nt] = __builtin_amdgcn_mfma_f32_16x16x32_bf16(af[mt], bfr[0][nt], acc[4 + mt][nt], 0, 0, 0);
            }
            __builtin_amdgcn_s_setprio(0);
            __builtin_amdgcn_s_barrier();
        }
        // ---- Phase 4: (mh=1, kh=1) + end-of-tile vmcnt ----
        {
            const int cs = ((4 + quad) ^ aswz) * 8;
#pragma unroll
            for (int mt = 0; mt < 4; mt++)
                af[mt] = *(const bf16x8*)(al + (wm * 128 + 64 + mt * 16 + ln) * 64 + cs);
            __builtin_amdgcn_s_barrier();
            asm volatile("s_waitcnt lgkmcnt(0)" ::: "memory");
            __builtin_amdgcn_sched_barrier(0);
            __builtin_amdgcn_s_setprio(1);
#pragma unroll
            for (int mt = 0; mt < 4; mt++) {
#pragma unroll
                for (int nt = 0; nt < 4; nt++)
                    acc[4 + mt][nt] = __builtin_amdgcn_mfma_f32_16x16x32_bf16(af[mt], bfr[1][nt], acc[4 + mt][nt], 0, 0, 0);
            }
            __builtin_amdgcn_s_setprio(0);
            if (t + 1 < NT) { asm volatile("s_waitcnt vmcnt(0)" ::: "memory"); }
            __builtin_amdgcn_s_barrier();
            asm volatile("" ::: "memory");
        }
        rb ^= 1;
    }

    const int row0 = bm * 256 + wm * 128 + quad * 4;
    const int col0 = bn * 256 + wn * 64 + ln;
    if (OUT_BF16) {
        unsigned short* C = (unsigned short*)Cv;
#pragma unroll
        for (int mt = 0; mt < 8; mt++) {
#pragma unroll
            for (int nt = 0; nt < 4; nt++) {
#pragma unroll
                for (int rr = 0; rr < 4; rr++)
                    C[(size_t)(row0 + mt * 16 + rr) * N + col0 + nt * 16] = f2bf(acc[mt][nt][rr]);
            }
        }
    } else {
        float* C = (float*)Cv;
#pragma unroll
        for (int mt = 0; mt < 8; mt++) {
#pragma unroll
            for (int nt = 0; nt < 4; nt++) {
#pragma unroll
                for (int rr = 0; rr < 4; rr++)
                    C[(size_t)(row0 + mt * 16 + rr) * N + col0 + nt * 16] = acc[mt][nt][rr];
            }
        }
    }
}

// ---------------- RoPE for Q (scaled) and K ----------------
__global__ __launch_bounds__(256) void rope_kernel(const unsigned short* __restrict__ qkv,
                                                   const float* __restrict__ freqs,
                                                   const int* __restrict__ kvidx,
                                                   unsigned short* __restrict__ Qb,
                                                   unsigned short* __restrict__ Kb) {
    int t = blockIdx.x * 256 + threadIdx.x;
    int d = t & 127;
    int t2 = t >> 7;
    int hh = t2 % 24;
    int pos = t2 / 24;
    if (pos >= S_LEN) return;
    float2 cs = *(const float2*)(freqs + ((size_t)pos * 128 + d) * 2);
    if (hh < NHQ) {
        const unsigned short* src = qkv + (size_t)pos * QKV_COLS + hh * HDIM + d;
        float x1 = bf2f(src[0]), x2 = bf2f(src[128]);
        float o1 = (x1 * cs.x - x2 * cs.y) * 0.0625f;
        float o2 = (x1 * cs.y + x2 * cs.x) * 0.0625f;
        unsigned short* dst = Qb + ((size_t)hh * S_LEN + pos) * HDIM + d;
        dst[0] = f2bf(o1);
        dst[128] = f2bf(o2);
    } else {
        int kvh = hh - NHQ;
        const unsigned short* src = qkv + (size_t)pos * QKV_COLS + NHQ * HDIM + kvh * HDIM + d;
        float x1 = bf2f(src[0]), x2 = bf2f(src[128]);
        float o1 = x1 * cs.x - x2 * cs.y;
        float o2 = x1 * cs.y + x2 * cs.x;
        int wpos = kvidx[pos];
        unsigned short* dst = Kb + ((size_t)kvh * S_LEN + wpos) * HDIM + d;
        dst[0] = f2bf(o1);
        dst[128] = f2bf(o2);
    }
}

// ---------------- V transpose ----------------
__global__ __launch_bounds__(256) void vtrans_kernel(const unsigned short* __restrict__ qkv,
                                                     const int* __restrict__ kvidx,
                                                     unsigned short* __restrict__ Vbt) {
    __shared__ unsigned short T[64][72];
    int pos0 = blockIdx.x * 64;
    int c0 = blockIdx.y * 64;
    int a = threadIdx.x >> 6;
    int b = threadIdx.x & 63;
#pragma unroll
    for (int r = 0; r < 16; r++) {
        int pl = r * 4 + a;
        T[pl][b] = qkv[(size_t)(pos0 + pl) * QKV_COLS + 6144 + c0 + b];
    }
    __syncthreads();
    int wpos = kvidx[pos0 + b];
#pragma unroll
    for (int r = 0; r < 16; r++) {
        int cl = r * 4 + a;
        Vbt[(size_t)(c0 + cl) * S_LEN + wpos] = T[b][cl];
    }
}

// ---------------- flash attention v7: 32x32 MFMA, no atomics, 2-ahead pipeline ----
// (passed rounds 5-7 — unchanged)
__global__ __launch_bounds__(256, 1) void attn_kernel(const unsigned short* __restrict__ Qb,
                                                      const unsigned short* __restrict__ Kb,
                                                      const unsigned short* __restrict__ Vbt,
                                                      unsigned short* __restrict__ attn_out) {
    __shared__ __align__(16) unsigned short Kl[3][32 * 256];
    __shared__ __align__(16) unsigned short Vl[3][256 * 32];
    __shared__ __align__(16) unsigned short Plb[4][1024];

    const int h = blockIdx.x & 15;
    const int qb = 23 - (blockIdx.x >> 4);

    const int kv = h >> 1;
    const int q0 = qb * 128;
    const int tid = threadIdx.x;
    const int wid = tid >> 6, lane = tid & 63;
    const int ln32 = lane & 31, hi = lane >> 5;
    const int qw0 = q0 + wid * 32;

    bf16x8 qf[16];
    {
        const unsigned short* qrow = Qb + ((size_t)h * S_LEN + qw0 + ln32) * HDIM + hi * 8;
#pragma unroll
        for (int s = 0; s < 16; s++)
            qf[s] = *(const bf16x8*)(qrow + s * 16);
    }

    f32x16 pacc[8];
#pragma unroll
    for (int dt = 0; dt < 8; dt++) {
#pragma unroll
        for (int i = 0; i < 16; i++) pacc[dt][i] = 0.f;
    }
    float ps[16];
#pragma unroll
    for (int r = 0; r < 16; r++) ps[r] = 0.f;

    const int imin = qw0;
    const int imax = qw0 + 31;

    const int t_lo = (q0 >= WIN) ? ((q0 - (WIN - 1)) >> 5) : 0;
    const int t_hi = (q0 + 127) >> 5;
    const int ts = t_lo;
    const int te = t_hi + 1;

    const unsigned short* kSrcA = Kb + ((size_t)kv * S_LEN + (tid >> 5)) * HDIM
                                  + ((tid & 31) ^ ((tid >> 5) & 7)) * 8;
    const unsigned short* vSrcA = Vbt + ((size_t)kv * HDIM + (tid >> 2)) * S_LEN
                                  + ((tid & 3) ^ ((tid >> 3) & 3)) * 8;

    auto STAGE = [&](int tile, int b) {
        const int p0x = tile * 32;
        const unsigned short* ksg = kSrcA + (size_t)p0x * HDIM;
        const unsigned short* vsg = vSrcA + p0x;
#pragma unroll
        for (int c = 0; c < 4; c++)
            async16(ksg + (size_t)(c * 8) * HDIM, &Kl[b][(c * 256 + tid) * 8]);
#pragma unroll
        for (int c = 0; c < 4; c++)
            async16(vsg + (size_t)(c * 64) * S_LEN, &Vl[b][(c * 256 + tid) * 8]);
    };

    STAGE(ts, 0);
    STAGE(ts + 1, 1);

    unsigned short* plw = &Plb[wid][0];
    const int kswz = ln32 & 7;
    int rb = 0;

    for (int tt = ts; tt < te; tt++) {
        if (tt + 1 < te) { asm volatile("s_waitcnt vmcnt(8)" ::: "memory"); }
        else             { asm volatile("s_waitcnt vmcnt(0)" ::: "memory"); }
        __builtin_amdgcn_s_barrier();
        asm volatile("" ::: "memory");

        if (tt + 2 < te) {
            const int wb = (rb >= 1) ? rb - 1 : 2;
            STAGE(tt + 2, wb);
        }

        const int p0 = tt * 32;
        const bool live = (p0 <= imax) && (p0 + 31 >= imin - WIN + 1);
        if (live) {
            const unsigned short* kb = Kl[rb];
            f32x16 sacc;
#pragma unroll
            for (int i = 0; i < 16; i++) sacc[i] = 0.f;
#pragma unroll
            for (int s = 0; s < 16; s++) {
                bf16x8 kf = *(const bf16x8*)(kb + ln32 * 256 + ((((s << 1) + hi) ^ kswz) << 3));
                sacc = __builtin_amdgcn_mfma_f32_32x32x16_bf16(qf[s], kf, sacc, 0, 0, 0);
            }

            const bool full = (p0 + 31 <= imin) && (p0 >= imax - WIN + 1);
#pragma unroll
            for (int r = 0; r < 16; r++) {
                float z = __expf(sacc[r] * 0.04f);
                float t = fmaf(-100.f, __builtin_amdgcn_rcpf(z + 1.f), 50.f);
                float p = __expf(t);
                const int qloc = (r & 3) + 8 * (r >> 2) + 4 * hi;
                if (!full) {
                    const int i = qw0 + qloc;
                    const int j = p0 + ln32;
                    p = ((j <= i) && (j + WIN > i)) ? p : 0.f;
                }
                ps[r] += p;
                plw[qloc * 32 + (((ln32 >> 3) ^ ((qloc >> 1) & 3)) << 3) + (ln32 & 7)] = f2bf(p);
            }

            bf16x8 pa0 = *(const bf16x8*)(plw + ln32 * 32 + ((hi ^ ((ln32 >> 1) & 3)) << 3));
            bf16x8 pa1 = *(const bf16x8*)(plw + ln32 * 32 + (((2 + hi) ^ ((ln32 >> 1) & 3)) << 3));
            const unsigned short* vb = Vl[rb];
#pragma unroll
            for (int dt = 0; dt < 8; dt++) {
                const int d = dt * 32 + ln32;
                const int vswz = (d >> 1) & 3;
                bf16x8 v0 = *(const bf16x8*)(vb + d * 32 + ((hi ^ vswz) << 3));
                pacc[dt] = __builtin_amdgcn_mfma_f32_32x32x16_bf16(pa0, v0, pacc[dt], 0, 0, 0);
                bf16x8 v1 = *(const bf16x8*)(vb + d * 32 + (((2 + hi) ^ vswz) << 3));
                pacc[dt] = __builtin_amdgcn_mfma_f32_32x32x16_bf16(pa1, v1, pacc[dt], 0, 0, 0);
            }
        }
        rb = (rb >= 2) ? 0 : rb + 1;
    }

#pragma unroll
    for (int r = 0; r < 16; r++) {
        float s = ps[r];
#pragma unroll
        for (int o = 1; o <= 16; o <<= 1)
            s += __shfl_xor(s, o);
        ps[r] = s;
    }

#pragma unroll
    for (int dt = 0; dt < 8; dt++) {
#pragma unroll
        for (int r = 0; r < 16; r++) {
            const int q = qw0 + (r & 3) + 8 * (r >> 2) + 4 * hi;
            float o = pacc[dt][r] * __builtin_amdgcn_rcpf(ps[r]);
            attn_out[(size_t)q * 4096 + h * HDIM + dt * 32 + ln32] = f2bf(o);
        }
    }
}

// ---------------- launch ----------------
extern "C" void kernel_launch(void* const* d_in, const int* in_sizes, int n_in,
                              void* d_out, int out_size, void* d_ws, size_t ws_size,
                              hipStream_t stream) {
    (void)in_sizes; (void)n_in; (void)out_size; (void)ws_size;
    const float* hidden = (const float*)d_in[0];
    const float* freqs  = (const float*)d_in[1];
    const int* kvidx    = (const int*)d_in[2];
    const float* qkv_w  = (const float*)d_in[6];
    const float* o_w    = (const float*)d_in[7];
    float* out = (float*)d_out;

    char* ws = (char*)d_ws;
    unsigned short* hs_bf   = (unsigned short*)(ws);                 // 22.0 MB
    unsigned short* w1_bf   = (unsigned short*)(ws + 22020096);
    unsigned short* w2_bf   = (unsigned short*)(ws + 80740352);
    unsigned short* qkv_bf  = (unsigned short*)(ws + 110100480);     // 50.3 MB
    unsigned short* Qb      = (unsigned short*)(ws + 160432128);
    unsigned short* Kb      = (unsigned short*)(ws + 185597952);
    unsigned short* Vbt     = (unsigned short*)(ws + 198180864);
    unsigned short* attn_bf = (unsigned short*)(ws + 210763776);

    cast_bf16_kernel<<<10752, 256, 0, stream>>>(hidden, hs_bf, 11010048);
    cast_bf16_kernel<<<28672, 256, 0, stream>>>(qkv_w, w1_bf, 29360128);
    cast_bf16_kernel<<<14336, 256, 0, stream>>>(o_w, w2_bf, 14680064);

    gemm_bt<1><<<dim3(32, 12), 512, 0, stream>>>(hs_bf, w1_bf, (void*)qkv_bf, 8192, 3584);

    rope_kernel<<<36864, 256, 0, stream>>>(qkv_bf, freqs, kvidx, Qb, Kb);
    vtrans_kernel<<<dim3(48, 32), 256, 0, stream>>>(qkv_bf, kvidx, Vbt);

    attn_kernel<<<384, 256, 0, stream>>>(Qb, Kb, Vbt, attn_bf);

    gemm_bt<0><<<dim3(14, 12), 512, 0, stream>>>(attn_bf, w2_bf, (void*)out, 3584, 4096);
}

// Round 9
// 866.390 us; speedup vs baseline: 1.0844x; 1.0844x over previous
//
#include <hip/hip_runtime.h>

#define S_LEN 3072
#define NHQ 16
#define NKVH 8
#define HDIM 256
#define WIN 2048
#define QKV_COLS 8192

typedef __bf16 bf16x8 __attribute__((ext_vector_type(8)));
typedef float f32x4 __attribute__((ext_vector_type(4)));
typedef float f32x16 __attribute__((ext_vector_type(16)));

__device__ __forceinline__ unsigned short f2bf(float f) {
    union { float f; unsigned u; } v; v.f = f;
    unsigned r = v.u + 0x7FFFu + ((v.u >> 16) & 1u);
    return (unsigned short)(r >> 16);
}
__device__ __forceinline__ float bf2f(unsigned short u) {
    union { unsigned u; float f; } v; v.u = ((unsigned)u) << 16; return v.f;
}

typedef __attribute__((address_space(3))) void lds_void_t;
typedef const __attribute__((address_space(1))) void glb_void_t;
__device__ __forceinline__ void async16(const void* g, void* l) {
    __builtin_amdgcn_global_load_lds((glb_void_t*)g, (lds_void_t*)l, 16, 0, 0);
}

// ---------------- fp32 -> bf16 cast ----------------
__global__ __launch_bounds__(256) void cast_bf16_kernel(const float* __restrict__ src,
                                                        unsigned short* __restrict__ dst,
                                                        int n) {
    int i = (blockIdx.x * 256 + threadIdx.x) * 4;
    if (i >= n) return;
    float4 v = *(const float4*)(src + i);
    ushort4 o;
    o.x = f2bf(v.x); o.y = f2bf(v.y); o.z = f2bf(v.z); o.w = f2bf(v.w);
    *(ushort4*)(dst + i) = o;
}

// ---------------- bf16 GEMM v11: v8 pipeline + T2 bank swizzle ----------------
// v8 (round 6, verified 251us): 128x128 tile, 3-buffer LDS, 2-ahead STAGE,
// counted vmcnt(4), one raw s_barrier per K-step. Its measured limiter:
// SQ_LDS_BANK_CONFLICT 2.2e7 (64B rows -> 16 lanes on 2 bank groups, 8-way).
// v11 adds the v9-VERIFIED swizzle (conflicts 2.2e7 -> 0 there): slot
// involution slot ^= (row>>1)&3 within each 4-slot (64B) row — rows r,r+8
// still alias = 2-way = free (m136). Both-sides rule: pre-swizzled global
// source column ((lane&3)^((lane>>3)&3))*8 (call-invariant: row bases are
// multiples of 16) + swizzled read slot quad^((ln>>1)&3).
// XCD-aware bijective block swizzle kept (1536%8==0, 672%8==0).
template <int OUT_BF16>
__global__ __launch_bounds__(256) void gemm_bt(const unsigned short* __restrict__ A,
                                               const unsigned short* __restrict__ B,
                                               void* __restrict__ Cv,
                                               int N, int K) {
    __shared__ __align__(16) unsigned short At[3][128 * 32];
    __shared__ __align__(16) unsigned short Bt[3][128 * 32];
    const int tid = threadIdx.x;
    const int wid = tid >> 6, lane = tid & 63;
    const int ln = lane & 15, quad = lane >> 4;

    int bm, bn;
    {
        const int nwg = gridDim.x * gridDim.y;
        int orig = blockIdx.y * gridDim.x + blockIdx.x;
        int wg = orig;
        if ((nwg & 7) == 0) {
            const int cpx = nwg >> 3;
            wg = (orig & 7) * cpx + (orig >> 3);
        }
        bm = wg / gridDim.x;
        bn = wg % gridDim.x;
    }
    const int wm = wid >> 1, wn = wid & 1;

    const f32x4 fzero = {0.f, 0.f, 0.f, 0.f};
    f32x4 acc[4][4];
#pragma unroll
    for (int i = 0; i < 4; i++) {
#pragma unroll
        for (int j = 0; j < 4; j++) acc[i][j] = fzero;
    }

    // pre-swizzled source: lane l stages source chunk (l&3)^((l>>3)&3) of its
    // row into LDS slot (l&3) -> LDS slot s of row r holds chunk s^((r>>1)&3).
    const unsigned short* gA = A + (size_t)(bm * 128 + wid * 32 + (lane >> 2)) * K
                               + (((lane & 3) ^ ((lane >> 3) & 3)) * 8);
    const unsigned short* gB = B + (size_t)(bn * 128 + wid * 32 + (lane >> 2)) * K
                               + (((lane & 3) ^ ((lane >> 3) & 3)) * 8);
    const int lbase = wid * 32 * 32;   // wave-uniform LDS base (HW adds lane*16B)

    auto STAGE = [&](int k0, int b) {
        async16(gA + k0,          &At[b][lbase]);
        async16(gA + k0 + 16 * K, &At[b][lbase + 16 * 32]);
        async16(gB + k0,          &Bt[b][lbase]);
        async16(gB + k0 + 16 * K, &Bt[b][lbase + 16 * 32]);
    };

    const int NT = K >> 5;             // K/32 steps (>= 3 for all launches)
    STAGE(0, 0);
    STAGE(32, 1);
    int rb = 0;
    const int rswz = (ln >> 1) & 3;    // (row>>1)&3 for all fragment rows

    for (int t = 0; t < NT; ++t) {
        // counted wait: this tile's 4 DMAs done (FIFO); next tile's 4 may fly.
        if (t + 1 < NT) { asm volatile("s_waitcnt vmcnt(4)" ::: "memory"); }
        else            { asm volatile("s_waitcnt vmcnt(0)" ::: "memory"); }
        __builtin_amdgcn_s_barrier();
        asm volatile("" ::: "memory");

        // 2-ahead prefetch into the buffer last read at iter t-1 (all waves
        // passed the barrier above after finishing that read -> safe).
        if (t + 2 < NT) {
            const int wb = (rb >= 1) ? rb - 1 : 2;   // (rb+2)%3
            STAGE((t + 2) * 32, wb);
        }

        const int cs = (quad ^ rswz) * 8;            // swizzled slot offset
        bf16x8 af[4], bfr[4];
#pragma unroll
        for (int mt = 0; mt < 4; mt++)
            af[mt] = *(const bf16x8*)(&At[rb][(wm * 64 + mt * 16 + ln) * 32 + cs]);
#pragma unroll
        for (int nt = 0; nt < 4; nt++)
            bfr[nt] = *(const bf16x8*)(&Bt[rb][(wn * 64 + nt * 16 + ln) * 32 + cs]);
#pragma unroll
        for (int mt = 0; mt < 4; mt++) {
#pragma unroll
            for (int nt = 0; nt < 4; nt++)
                acc[mt][nt] = __builtin_amdgcn_mfma_f32_16x16x32_bf16(af[mt], bfr[nt], acc[mt][nt], 0, 0, 0);
        }
        rb = (rb >= 2) ? 0 : rb + 1;
    }

    const int row0 = bm * 128 + wm * 64 + quad * 4;
    const int col0 = bn * 128 + wn * 64 + ln;
    if (OUT_BF16) {
        unsigned short* C = (unsigned short*)Cv;
#pragma unroll
        for (int mt = 0; mt < 4; mt++) {
#pragma unroll
            for (int nt = 0; nt < 4; nt++) {
#pragma unroll
                for (int rr = 0; rr < 4; rr++)
                    C[(size_t)(row0 + mt * 16 + rr) * N + col0 + nt * 16] = f2bf(acc[mt][nt][rr]);
            }
        }
    } else {
        float* C = (float*)Cv;
#pragma unroll
        for (int mt = 0; mt < 4; mt++) {
#pragma unroll
            for (int nt = 0; nt < 4; nt++) {
#pragma unroll
                for (int rr = 0; rr < 4; rr++)
                    C[(size_t)(row0 + mt * 16 + rr) * N + col0 + nt * 16] = acc[mt][nt][rr];
            }
        }
    }
}

// ---------------- RoPE for Q (scaled) and K ----------------
__global__ __launch_bounds__(256) void rope_kernel(const unsigned short* __restrict__ qkv,
                                                   const float* __restrict__ freqs,
                                                   const int* __restrict__ kvidx,
                                                   unsigned short* __restrict__ Qb,
                                                   unsigned short* __restrict__ Kb) {
    int t = blockIdx.x * 256 + threadIdx.x;
    int d = t & 127;
    int t2 = t >> 7;
    int hh = t2 % 24;
    int pos = t2 / 24;
    if (pos >= S_LEN) return;
    float2 cs = *(const float2*)(freqs + ((size_t)pos * 128 + d) * 2);
    if (hh < NHQ) {
        const unsigned short* src = qkv + (size_t)pos * QKV_COLS + hh * HDIM + d;
        float x1 = bf2f(src[0]), x2 = bf2f(src[128]);
        float o1 = (x1 * cs.x - x2 * cs.y) * 0.0625f;
        float o2 = (x1 * cs.y + x2 * cs.x) * 0.0625f;
        unsigned short* dst = Qb + ((size_t)hh * S_LEN + pos) * HDIM + d;
        dst[0] = f2bf(o1);
        dst[128] = f2bf(o2);
    } else {
        int kvh = hh - NHQ;
        const unsigned short* src = qkv + (size_t)pos * QKV_COLS + NHQ * HDIM + kvh * HDIM + d;
        float x1 = bf2f(src[0]), x2 = bf2f(src[128]);
        float o1 = x1 * cs.x - x2 * cs.y;
        float o2 = x1 * cs.y + x2 * cs.x;
        int wpos = kvidx[pos];
        unsigned short* dst = Kb + ((size_t)kvh * S_LEN + wpos) * HDIM + d;
        dst[0] = f2bf(o1);
        dst[128] = f2bf(o2);
    }
}

// ---------------- V transpose ----------------
__global__ __launch_bounds__(256) void vtrans_kernel(const unsigned short* __restrict__ qkv,
                                                     const int* __restrict__ kvidx,
                                                     unsigned short* __restrict__ Vbt) {
    __shared__ unsigned short T[64][72];
    int pos0 = blockIdx.x * 64;
    int c0 = blockIdx.y * 64;
    int a = threadIdx.x >> 6;
    int b = threadIdx.x & 63;
#pragma unroll
    for (int r = 0; r < 16; r++) {
        int pl = r * 4 + a;
        T[pl][b] = qkv[(size_t)(pos0 + pl) * QKV_COLS + 6144 + c0 + b];
    }
    __syncthreads();
    int wpos = kvidx[pos0 + b];
#pragma unroll
    for (int r = 0; r < 16; r++) {
        int cl = r * 4 + a;
        Vbt[(size_t)(c0 + cl) * S_LEN + wpos] = T[b][cl];
    }
}

// ---------------- flash attention v7: 32x32 MFMA, no atomics, 2-ahead pipeline ----
// (passed rounds 5-8 — unchanged)
__global__ __launch_bounds__(256, 1) void attn_kernel(const unsigned short* __restrict__ Qb,
                                                      const unsigned short* __restrict__ Kb,
                                                      const unsigned short* __restrict__ Vbt,
                                                      unsigned short* __restrict__ attn_out) {
    __shared__ __align__(16) unsigned short Kl[3][32 * 256];
    __shared__ __align__(16) unsigned short Vl[3][256 * 32];
    __shared__ __align__(16) unsigned short Plb[4][1024];

    const int h = blockIdx.x & 15;
    const int qb = 23 - (blockIdx.x >> 4);

    const int kv = h >> 1;
    const int q0 = qb * 128;
    const int tid = threadIdx.x;
    const int wid = tid >> 6, lane = tid & 63;
    const int ln32 = lane & 31, hi = lane >> 5;
    const int qw0 = q0 + wid * 32;

    bf16x8 qf[16];
    {
        const unsigned short* qrow = Qb + ((size_t)h * S_LEN + qw0 + ln32) * HDIM + hi * 8;
#pragma unroll
        for (int s = 0; s < 16; s++)
            qf[s] = *(const bf16x8*)(qrow + s * 16);
    }

    f32x16 pacc[8];
#pragma unroll
    for (int dt = 0; dt < 8; dt++) {
#pragma unroll
        for (int i = 0; i < 16; i++) pacc[dt][i] = 0.f;
    }
    float ps[16];
#pragma unroll
    for (int r = 0; r < 16; r++) ps[r] = 0.f;

    const int imin = qw0;
    const int imax = qw0 + 31;

    const int t_lo = (q0 >= WIN) ? ((q0 - (WIN - 1)) >> 5) : 0;
    const int t_hi = (q0 + 127) >> 5;
    const int ts = t_lo;
    const int te = t_hi + 1;

    const unsigned short* kSrcA = Kb + ((size_t)kv * S_LEN + (tid >> 5)) * HDIM
                                  + ((tid & 31) ^ ((tid >> 5) & 7)) * 8;
    const unsigned short* vSrcA = Vbt + ((size_t)kv * HDIM + (tid >> 2)) * S_LEN
                                  + ((tid & 3) ^ ((tid >> 3) & 3)) * 8;

    auto STAGE = [&](int tile, int b) {
        const int p0x = tile * 32;
        const unsigned short* ksg = kSrcA + (size_t)p0x * HDIM;
        const unsigned short* vsg = vSrcA + p0x;
#pragma unroll
        for (int c = 0; c < 4; c++)
            async16(ksg + (size_t)(c * 8) * HDIM, &Kl[b][(c * 256 + tid) * 8]);
#pragma unroll
        for (int c = 0; c < 4; c++)
            async16(vsg + (size_t)(c * 64) * S_LEN, &Vl[b][(c * 256 + tid) * 8]);
    };

    STAGE(ts, 0);
    STAGE(ts + 1, 1);

    unsigned short* plw = &Plb[wid][0];
    const int kswz = ln32 & 7;
    int rb = 0;

    for (int tt = ts; tt < te; tt++) {
        if (tt + 1 < te) { asm volatile("s_waitcnt vmcnt(8)" ::: "memory"); }
        else             { asm volatile("s_waitcnt vmcnt(0)" ::: "memory"); }
        __builtin_amdgcn_s_barrier();
        asm volatile("" ::: "memory");

        if (tt + 2 < te) {
            const int wb = (rb >= 1) ? rb - 1 : 2;
            STAGE(tt + 2, wb);
        }

        const int p0 = tt * 32;
        const bool live = (p0 <= imax) && (p0 + 31 >= imin - WIN + 1);
        if (live) {
            const unsigned short* kb = Kl[rb];
            f32x16 sacc;
#pragma unroll
            for (int i = 0; i < 16; i++) sacc[i] = 0.f;
#pragma unroll
            for (int s = 0; s < 16; s++) {
                bf16x8 kf = *(const bf16x8*)(kb + ln32 * 256 + ((((s << 1) + hi) ^ kswz) << 3));
                sacc = __builtin_amdgcn_mfma_f32_32x32x16_bf16(qf[s], kf, sacc, 0, 0, 0);
            }

            const bool full = (p0 + 31 <= imin) && (p0 >= imax - WIN + 1);
#pragma unroll
            for (int r = 0; r < 16; r++) {
                float z = __expf(sacc[r] * 0.04f);
                float t = fmaf(-100.f, __builtin_amdgcn_rcpf(z + 1.f), 50.f);
                float p = __expf(t);
                const int qloc = (r & 3) + 8 * (r >> 2) + 4 * hi;
                if (!full) {
                    const int i = qw0 + qloc;
                    const int j = p0 + ln32;
                    p = ((j <= i) && (j + WIN > i)) ? p : 0.f;
                }
                ps[r] += p;
                plw[qloc * 32 + (((ln32 >> 3) ^ ((qloc >> 1) & 3)) << 3) + (ln32 & 7)] = f2bf(p);
            }

            bf16x8 pa0 = *(const bf16x8*)(plw + ln32 * 32 + ((hi ^ ((ln32 >> 1) & 3)) << 3));
            bf16x8 pa1 = *(const bf16x8*)(plw + ln32 * 32 + (((2 + hi) ^ ((ln32 >> 1) & 3)) << 3));
            const unsigned short* vb = Vl[rb];
#pragma unroll
            for (int dt = 0; dt < 8; dt++) {
                const int d = dt * 32 + ln32;
                const int vswz = (d >> 1) & 3;
                bf16x8 v0 = *(const bf16x8*)(vb + d * 32 + ((hi ^ vswz) << 3));
                pacc[dt] = __builtin_amdgcn_mfma_f32_32x32x16_bf16(pa0, v0, pacc[dt], 0, 0, 0);
                bf16x8 v1 = *(const bf16x8*)(vb + d * 32 + (((2 + hi) ^ vswz) << 3));
                pacc[dt] = __builtin_amdgcn_mfma_f32_32x32x16_bf16(pa1, v1, pacc[dt], 0, 0, 0);
            }
        }
        rb = (rb >= 2) ? 0 : rb + 1;
    }

#pragma unroll
    for (int r = 0; r < 16; r++) {
        float s = ps[r];
#pragma unroll
        for (int o = 1; o <= 16; o <<= 1)
            s += __shfl_xor(s, o);
        ps[r] = s;
    }

#pragma unroll
    for (int dt = 0; dt < 8; dt++) {
#pragma unroll
        for (int r = 0; r < 16; r++) {
            const int q = qw0 + (r & 3) + 8 * (r >> 2) + 4 * hi;
            float o = pacc[dt][r] * __builtin_amdgcn_rcpf(ps[r]);
            attn_out[(size_t)q * 4096 + h * HDIM + dt * 32 + ln32] = f2bf(o);
        }
    }
}

// ---------------- launch ----------------
extern "C" void kernel_launch(void* const* d_in, const int* in_sizes, int n_in,
                              void* d_out, int out_size, void* d_ws, size_t ws_size,
                              hipStream_t stream) {
    (void)in_sizes; (void)n_in; (void)out_size; (void)ws_size;
    const float* hidden = (const float*)d_in[0];
    const float* freqs  = (const float*)d_in[1];
    const int* kvidx    = (const int*)d_in[2];
    const float* qkv_w  = (const float*)d_in[6];
    const float* o_w    = (const float*)d_in[7];
    float* out = (float*)d_out;

    char* ws = (char*)d_ws;
    unsigned short* hs_bf   = (unsigned short*)(ws);                 // 22.0 MB
    unsigned short* w1_bf   = (unsigned short*)(ws + 22020096);
    unsigned short* w2_bf   = (unsigned short*)(ws + 80740352);
    unsigned short* qkv_bf  = (unsigned short*)(ws + 110100480);     // 50.3 MB
    unsigned short* Qb      = (unsigned short*)(ws + 160432128);
    unsigned short* Kb      = (unsigned short*)(ws + 185597952);
    unsigned short* Vbt     = (unsigned short*)(ws + 198180864);
    unsigned short* attn_bf = (unsigned short*)(ws + 210763776);

    cast_bf16_kernel<<<10752, 256, 0, stream>>>(hidden, hs_bf, 11010048);
    cast_bf16_kernel<<<28672, 256, 0, stream>>>(qkv_w, w1_bf, 29360128);
    cast_bf16_kernel<<<14336, 256, 0, stream>>>(o_w, w2_bf, 14680064);

    gemm_bt<1><<<dim3(64, 24), 256, 0, stream>>>(hs_bf, w1_bf, (void*)qkv_bf, 8192, 3584);

    rope_kernel<<<36864, 256, 0, stream>>>(qkv_bf, freqs, kvidx, Qb, Kb);
    vtrans_kernel<<<dim3(48, 32), 256, 0, stream>>>(qkv_bf, kvidx, Vbt);

    attn_kernel<<<384, 256, 0, stream>>>(Qb, Kb, Vbt, attn_bf);

    gemm_bt<0><<<dim3(28, 24), 256, 0, stream>>>(attn_bf, w2_bf, (void*)out, 3584, 4096);
}